// Round 9
// baseline (190.453 us; speedup 1.0000x reference)
//
#include <hip/hip_runtime.h>
#include <cstdint>

#define N_VIS   8192
#define N_ASSOC 4096
#define N_MOTOR 1024
#define IN_DIM  4096
#define T_STEPS 16

// ---------------- shared core: S[j][t] = sum_i W[j,i] * V[t][i] ----------------
// 256 threads: c = tid&63 (f4 column within chunk), g = tid>>6 (t-group of 4).
// 4 rows per block. 1 FMA per (element, t). W streamed from HBM once; V is L2-resident.
template<int COLS>
__global__ __launch_bounds__(256, 4) void matvec16_kernel(
        const float* __restrict__ Wg, const float* __restrict__ Vg,
        float* __restrict__ S) {
    constexpr int F4PR = COLS / 4;           // float4 per row
    constexpr int KIT  = COLS / 256;         // chunks of 64 f4
    const int c  = threadIdx.x & 63;
    const int g  = threadIdx.x >> 6;
    const int j0 = blockIdx.x * 4;
    const float4* W4 = (const float4*)(Wg + (size_t)j0 * COLS);
    const float4* V4 = (const float4*)Vg + (size_t)g * 4 * F4PR;

    float acc[4][4];
#pragma unroll
    for (int r = 0; r < 4; ++r)
#pragma unroll
        for (int q = 0; q < 4; ++q) acc[r][q] = 0.f;

#pragma unroll 2
    for (int k = 0; k < KIT; ++k) {
        const int idx = k * 64 + c;
        float4 w[4], v[4];
        w[0] = W4[idx];
        w[1] = W4[F4PR + idx];
        w[2] = W4[2 * F4PR + idx];
        w[3] = W4[3 * F4PR + idx];
        v[0] = V4[idx];
        v[1] = V4[F4PR + idx];
        v[2] = V4[2 * F4PR + idx];
        v[3] = V4[3 * F4PR + idx];
#pragma unroll
        for (int r = 0; r < 4; ++r)
#pragma unroll
            for (int q = 0; q < 4; ++q) {
                acc[r][q] = fmaf(w[r].x, v[q].x, acc[r][q]);
                acc[r][q] = fmaf(w[r].y, v[q].y, acc[r][q]);
                acc[r][q] = fmaf(w[r].z, v[q].z, acc[r][q]);
                acc[r][q] = fmaf(w[r].w, v[q].w, acc[r][q]);
            }
    }
#pragma unroll
    for (int r = 0; r < 4; ++r)
#pragma unroll
        for (int q = 0; q < 4; ++q) {
            float a = acc[r][q];
            for (int o = 32; o; o >>= 1) a += __shfl_down(a, o, 64);
            acc[r][q] = a;
        }
    if (c == 0) {
#pragma unroll
        for (int r = 0; r < 4; ++r)
#pragma unroll
            for (int q = 0; q < 4; ++q)
                S[(size_t)(j0 + r) * 16 + g * 4 + q] = acc[r][q];
    }
}

// ---------------- visual LIF + spike expansion (one thread per visual row) ----------------
__global__ __launch_bounds__(256) void vlif_kernel(
        const float* __restrict__ S1, const float* __restrict__ noise,
        const float* __restrict__ b, unsigned* __restrict__ vmask,
        float* __restrict__ V) {
    const int i = blockIdx.x * 256 + threadIdx.x;
    float a[T_STEPS];
#pragma unroll
    for (int t = 0; t < T_STEPS; ++t) a[t] = S1[(size_t)i * 16 + t];
    const float bb = b[i];
    float v = 0.f;
    unsigned msk = 0;
#pragma unroll
    for (int t = 0; t < T_STEPS; ++t) {
        float logit = a[t] + bb;
        float rate = 1.0f / (1.0f + expf(-logit));
        float u = noise[t * N_VIS + i];
        float ins = (u < rate * 0.3f) ? 1.0f : 0.0f;
        v = v * 0.95f + ins;
        if (v > 1.0f) { msk |= (1u << t); v = 0.f; }
    }
    vmask[i] = msk;
#pragma unroll
    for (int t = 0; t < T_STEPS; ++t)
        V[t * N_VIS + i] = (float)((msk >> t) & 1u);
}

// ---------------- K table: K[t][r] = sum_{s=r..t-1} g_s * d_s*0.1*0.01*C[s][r] ----------------
__global__ void ktab_kernel(const float* __restrict__ dop, float* __restrict__ K) {
    __shared__ float C[256];
    __shared__ float sd[16];
    __shared__ unsigned sg[16];
    const int p = threadIdx.x;
    if (p < 16) {
        float d = dop[p];
        sd[p] = d;
        sg[p] = (fabsf(d) > 0.1f) ? 1u : 0u;
    }
    __syncthreads();
    {
        const int s = p >> 4, r = p & 15;
        float c = 0.f;
        if (s >= r) {
            c = 1.f;
            for (int u = r; u < s; ++u) {
                if (sg[u]) c *= 0.5f;
                c *= 0.998f;
            }
        }
        C[p] = c;
    }
    __syncthreads();
    {
        const int t = p >> 4, r = p & 15;
        float kk = 0.f;
        for (int s = r; s < t; ++s)
            if (sg[s]) kk += ((sd[s] * 0.1f) * 0.01f) * C[s * 16 + r];
        K[p] = kk;
    }
}

// ---------------- OVL[r][t] = popcount over mask words of bit_r & bit_t ----------------
__global__ void ovl_kernel(const unsigned* __restrict__ mask, int words_per_block,
                           int* __restrict__ ovl) {
    const int p = threadIdx.x;
    const int r = p >> 4, t = p & 15;
    const unsigned* w = mask + blockIdx.x * words_per_block;
    int c = 0;
    for (int i = 0; i < words_per_block; ++i)
        c += (int)((w[i] >> r) & (w[i] >> t) & 1u);
    atomicAdd(&ovl[p], c);
}

// ---------------- tiny sequential recursion; optionally expands spikes to outV ----------------
__global__ __launch_bounds__(64) void rec_kernel(
        const float* __restrict__ base, const int* __restrict__ ovl,
        const float* __restrict__ K, unsigned* __restrict__ mask_out,
        float* __restrict__ outp, int out_stride,
        float* __restrict__ outV, int n_rows) {
    __shared__ float KO[256];
    const int tid = threadIdx.x;
    for (int p = tid; p < 256; p += 64) {
        const int t = p >> 4, r = p & 15;
        KO[p] = K[p] * (float)ovl[r * 16 + t];
    }
    __syncthreads();

    const int j = blockIdx.x * 64 + tid;
    float br[T_STEPS];
#pragma unroll
    for (int t = 0; t < T_STEPS; ++t) br[t] = base[(size_t)j * 16 + t];

    float vmem = 0.f;
    unsigned am = 0;
#pragma unroll
    for (int t = 0; t < T_STEPS; ++t) {
        float I = br[t];
        for (int r = 0; r < t; ++r)
            if ((am >> r) & 1u) I += KO[t * 16 + r];
        vmem = vmem * 0.95f + I * 0.1f;
        const bool s = vmem > 1.0f;
        if (s) { vmem = 0.f; am |= (1u << t); }
        if (outp) outp[t * out_stride + j] = s ? 1.0f : 0.0f;
    }
    mask_out[j] = am;
    if (outV) {
#pragma unroll
        for (int t = 0; t < T_STEPS; ++t)
            outV[t * n_rows + j] = (float)((am >> t) & 1u);
    }
}

extern "C" void kernel_launch(void* const* d_in, const int* in_sizes, int n_in,
                              void* d_out, int out_size, void* d_ws, size_t ws_size,
                              hipStream_t stream) {
    const float* x     = (const float*)d_in[0];   // [16, 4096]
    const float* noise = (const float*)d_in[1];   // [16, 8192]
    const float* dop   = (const float*)d_in[2];   // [16]
    const float* W_enc = (const float*)d_in[3];   // [8192, 4096]
    const float* b_enc = (const float*)d_in[4];   // [8192]
    const float* W_va  = (const float*)d_in[5];   // [4096, 8192]
    const float* W_am  = (const float*)d_in[6];   // [1024, 4096]
    float* out = (float*)d_out;                   // [16, 1024] f32
    (void)in_sizes; (void)n_in; (void)out_size; (void)ws_size;

    char* ws = (char*)d_ws;
    size_t off = 0;
    unsigned* vmask = (unsigned*)(ws + off); off += N_VIS * 4;
    unsigned* amask = (unsigned*)(ws + off); off += N_ASSOC * 4;
    unsigned* mmask = (unsigned*)(ws + off); off += N_MOTOR * 4;
    float*    K     = (float*)(ws + off);    off += 256 * 4;
    int*      ovl_v = (int*)(ws + off);      off += 256 * 4;
    int*      ovl_a = (int*)(ws + off);      off += 256 * 4;
    float*    S1    = (float*)(ws + off);    off += (size_t)N_VIS   * 16 * 4;
    float*    S2    = (float*)(ws + off);    off += (size_t)N_ASSOC * 16 * 4;
    float*    S3    = (float*)(ws + off);    off += (size_t)N_MOTOR * 16 * 4;
    float*    Vv    = (float*)(ws + off);    off += (size_t)T_STEPS * N_VIS * 4;
    float*    Va    = (float*)(ws + off);    off += (size_t)T_STEPS * N_ASSOC * 4;

    hipMemsetAsync(ovl_v, 0, 2 * 256 * 4, stream);   // ovl_v and ovl_a are adjacent

    ktab_kernel<<<1, 256, 0, stream>>>(dop, K);
    // visual encoder: S1 = W_enc @ x^T  (x plays the role of the dense V matrix)
    matvec16_kernel<IN_DIM><<<N_VIS / 4, 256, 0, stream>>>(W_enc, x, S1);
    vlif_kernel<<<N_VIS / 256, 256, 0, stream>>>(S1, noise, b_enc, vmask, Vv);
    ovl_kernel<<<32, 256, 0, stream>>>(vmask, N_VIS / 32, ovl_v);
    // assoc layer
    matvec16_kernel<N_VIS><<<N_ASSOC / 4, 256, 0, stream>>>(W_va, Vv, S2);
    rec_kernel<<<N_ASSOC / 64, 64, 0, stream>>>(S2, ovl_v, K, amask, nullptr, 0, Va, N_ASSOC);
    ovl_kernel<<<16, 256, 0, stream>>>(amask, N_ASSOC / 16, ovl_a);
    // motor layer
    matvec16_kernel<N_ASSOC><<<N_MOTOR / 4, 256, 0, stream>>>(W_am, Va, S3);
    rec_kernel<<<N_MOTOR / 64, 64, 0, stream>>>(S3, ovl_a, K, mmask, out, N_MOTOR, nullptr, 0);
}

// Round 10
// 178.460 us; speedup vs baseline: 1.0672x; 1.0672x over previous
//
#include <hip/hip_runtime.h>
#include <cstdint>

#define N_VIS   8192
#define N_ASSOC 4096
#define N_MOTOR 1024
#define IN_DIM  4096
#define T_STEPS 16

// ---------------- shared core: Sp[sp][j][t] = sum_{i in seg sp} W[j,i] * V[t][i] ----------------
// 256 threads: c = tid&63 (f4 col within chunk), g = tid>>6 (t-group of 4). 4 rows per block.
// CS = split-K factor; partials are summed (ascending sp) in the consumer kernels.
template<int COLS, int CS>
__global__ __launch_bounds__(256, 4) void matvec16_kernel(
        const float* __restrict__ Wg, const float* __restrict__ Vg,
        float* __restrict__ Sp, int nrows) {
    constexpr int F4PR = COLS / 4;           // float4 per row
    constexpr int SEG4 = F4PR / CS;          // float4 per split segment
    constexpr int KIT  = SEG4 / 64;          // chunks of 64 f4
    const int c  = threadIdx.x & 63;
    const int g  = threadIdx.x >> 6;
    const int j0 = (blockIdx.x / CS) * 4;
    const int sp = blockIdx.x % CS;
    const float4* W4 = (const float4*)Wg + (size_t)j0 * F4PR + (size_t)sp * SEG4;
    const float4* V4 = (const float4*)Vg + (size_t)(g * 4) * F4PR + (size_t)sp * SEG4;

    float acc[4][4];
#pragma unroll
    for (int r = 0; r < 4; ++r)
#pragma unroll
        for (int q = 0; q < 4; ++q) acc[r][q] = 0.f;

#pragma unroll 4
    for (int k = 0; k < KIT; ++k) {
        const int idx = k * 64 + c;
        float4 w[4], v[4];
        w[0] = W4[idx];
        w[1] = W4[F4PR + idx];
        w[2] = W4[2 * F4PR + idx];
        w[3] = W4[3 * F4PR + idx];
        v[0] = V4[idx];
        v[1] = V4[F4PR + idx];
        v[2] = V4[2 * F4PR + idx];
        v[3] = V4[3 * F4PR + idx];
#pragma unroll
        for (int r = 0; r < 4; ++r)
#pragma unroll
            for (int q = 0; q < 4; ++q) {
                acc[r][q] = fmaf(w[r].x, v[q].x, acc[r][q]);
                acc[r][q] = fmaf(w[r].y, v[q].y, acc[r][q]);
                acc[r][q] = fmaf(w[r].z, v[q].z, acc[r][q]);
                acc[r][q] = fmaf(w[r].w, v[q].w, acc[r][q]);
            }
    }
#pragma unroll
    for (int r = 0; r < 4; ++r)
#pragma unroll
        for (int q = 0; q < 4; ++q) {
            float a = acc[r][q];
            for (int o = 32; o; o >>= 1) a += __shfl_down(a, o, 64);
            acc[r][q] = a;
        }
    if (c == 0) {
#pragma unroll
        for (int r = 0; r < 4; ++r)
#pragma unroll
            for (int q = 0; q < 4; ++q)
                Sp[((size_t)sp * nrows + j0 + r) * 16 + g * 4 + q] = acc[r][q];
    }
}

// ---------------- visual LIF + spike expansion (one thread per visual row) ----------------
// Sums the CS=2 encoder partials in ascending order, then runs the LIF.
__global__ __launch_bounds__(256) void vlif_kernel(
        const float* __restrict__ S1p, const float* __restrict__ noise,
        const float* __restrict__ b, unsigned* __restrict__ vmask,
        float* __restrict__ V) {
    const int i = blockIdx.x * 256 + threadIdx.x;
    float a[T_STEPS];
#pragma unroll
    for (int t = 0; t < T_STEPS; ++t)
        a[t] = S1p[(size_t)i * 16 + t] + S1p[((size_t)N_VIS + i) * 16 + t];
    const float bb = b[i];
    float v = 0.f;
    unsigned msk = 0;
#pragma unroll
    for (int t = 0; t < T_STEPS; ++t) {
        float logit = a[t] + bb;
        float rate = 1.0f / (1.0f + expf(-logit));
        float u = noise[t * N_VIS + i];
        float ins = (u < rate * 0.3f) ? 1.0f : 0.0f;
        v = v * 0.95f + ins;
        if (v > 1.0f) { msk |= (1u << t); v = 0.f; }
    }
    vmask[i] = msk;
#pragma unroll
    for (int t = 0; t < T_STEPS; ++t)
        V[t * N_VIS + i] = (float)((msk >> t) & 1u);
}

// ---------------- K table: K[t][r] = sum_{s=r..t-1} g_s * d_s*0.1*0.01*C[s][r] ----------------
__global__ void ktab_kernel(const float* __restrict__ dop, float* __restrict__ K) {
    __shared__ float C[256];
    __shared__ float sd[16];
    __shared__ unsigned sg[16];
    const int p = threadIdx.x;
    if (p < 16) {
        float d = dop[p];
        sd[p] = d;
        sg[p] = (fabsf(d) > 0.1f) ? 1u : 0u;
    }
    __syncthreads();
    {
        const int s = p >> 4, r = p & 15;
        float c = 0.f;
        if (s >= r) {
            c = 1.f;
            for (int u = r; u < s; ++u) {
                if (sg[u]) c *= 0.5f;
                c *= 0.998f;
            }
        }
        C[p] = c;
    }
    __syncthreads();
    {
        const int t = p >> 4, r = p & 15;
        float kk = 0.f;
        for (int s = r; s < t; ++s)
            if (sg[s]) kk += ((sd[s] * 0.1f) * 0.01f) * C[s * 16 + r];
        K[p] = kk;
    }
}

// ---------------- OVL[r][t] = popcount over mask words of bit_r & bit_t ----------------
__global__ void ovl_kernel(const unsigned* __restrict__ mask, int words_per_block,
                           int* __restrict__ ovl) {
    const int p = threadIdx.x;
    const int r = p >> 4, t = p & 15;
    const unsigned* w = mask + blockIdx.x * words_per_block;
    int c = 0;
    for (int i = 0; i < words_per_block; ++i)
        c += (int)((w[i] >> r) & (w[i] >> t) & 1u);
    atomicAdd(&ovl[p], c);
}

// ---------------- tiny sequential recursion; sums cs partials; optional spike expansion ----
__global__ __launch_bounds__(64) void rec_kernel(
        const float* __restrict__ base, const int* __restrict__ ovl,
        const float* __restrict__ K, unsigned* __restrict__ mask_out,
        float* __restrict__ outp, int out_stride,
        float* __restrict__ outV, int n_rows, int cs) {
    __shared__ float KO[256];
    const int tid = threadIdx.x;
    for (int p = tid; p < 256; p += 64) {
        const int t = p >> 4, r = p & 15;
        KO[p] = K[p] * (float)ovl[r * 16 + t];
    }
    __syncthreads();

    const int j = blockIdx.x * 64 + tid;
    float br[T_STEPS];
#pragma unroll
    for (int t = 0; t < T_STEPS; ++t) br[t] = base[(size_t)j * 16 + t];
#pragma unroll 1
    for (int s = 1; s < cs; ++s)
#pragma unroll
        for (int t = 0; t < T_STEPS; ++t)
            br[t] += base[((size_t)s * n_rows + j) * 16 + t];

    float vmem = 0.f;
    unsigned am = 0;
#pragma unroll
    for (int t = 0; t < T_STEPS; ++t) {
        float I = br[t];
        for (int r = 0; r < t; ++r)
            if ((am >> r) & 1u) I += KO[t * 16 + r];
        vmem = vmem * 0.95f + I * 0.1f;
        const bool s = vmem > 1.0f;
        if (s) { vmem = 0.f; am |= (1u << t); }
        if (outp) outp[t * out_stride + j] = s ? 1.0f : 0.0f;
    }
    mask_out[j] = am;
    if (outV) {
#pragma unroll
        for (int t = 0; t < T_STEPS; ++t)
            outV[t * n_rows + j] = (float)((am >> t) & 1u);
    }
}

extern "C" void kernel_launch(void* const* d_in, const int* in_sizes, int n_in,
                              void* d_out, int out_size, void* d_ws, size_t ws_size,
                              hipStream_t stream) {
    const float* x     = (const float*)d_in[0];   // [16, 4096]
    const float* noise = (const float*)d_in[1];   // [16, 8192]
    const float* dop   = (const float*)d_in[2];   // [16]
    const float* W_enc = (const float*)d_in[3];   // [8192, 4096]
    const float* b_enc = (const float*)d_in[4];   // [8192]
    const float* W_va  = (const float*)d_in[5];   // [4096, 8192]
    const float* W_am  = (const float*)d_in[6];   // [1024, 4096]
    float* out = (float*)d_out;                   // [16, 1024] f32
    (void)in_sizes; (void)n_in; (void)out_size; (void)ws_size;

    char* ws = (char*)d_ws;
    size_t off = 0;
    unsigned* vmask = (unsigned*)(ws + off); off += N_VIS * 4;
    unsigned* amask = (unsigned*)(ws + off); off += N_ASSOC * 4;
    unsigned* mmask = (unsigned*)(ws + off); off += N_MOTOR * 4;
    float*    K     = (float*)(ws + off);    off += 256 * 4;
    int*      ovl_v = (int*)(ws + off);      off += 256 * 4;
    int*      ovl_a = (int*)(ws + off);      off += 256 * 4;
    float*    S1    = (float*)(ws + off);    off += (size_t)2 * N_VIS   * 16 * 4;
    float*    S2    = (float*)(ws + off);    off += (size_t)4 * N_ASSOC * 16 * 4;
    float*    S3    = (float*)(ws + off);    off += (size_t)4 * N_MOTOR * 16 * 4;
    float*    Vv    = (float*)(ws + off);    off += (size_t)T_STEPS * N_VIS * 4;
    float*    Va    = (float*)(ws + off);    off += (size_t)T_STEPS * N_ASSOC * 4;

    hipMemsetAsync(ovl_v, 0, 2 * 256 * 4, stream);   // ovl_v and ovl_a are adjacent

    ktab_kernel<<<1, 256, 0, stream>>>(dop, K);
    // visual encoder: S1 = W_enc @ x^T  (x is the dense V matrix), CS=2
    matvec16_kernel<IN_DIM, 2><<<(N_VIS / 4) * 2, 256, 0, stream>>>(W_enc, x, S1, N_VIS);
    vlif_kernel<<<N_VIS / 256, 256, 0, stream>>>(S1, noise, b_enc, vmask, Vv);
    ovl_kernel<<<32, 256, 0, stream>>>(vmask, N_VIS / 32, ovl_v);
    // assoc layer, CS=4
    matvec16_kernel<N_VIS, 4><<<(N_ASSOC / 4) * 4, 256, 0, stream>>>(W_va, Vv, S2, N_ASSOC);
    rec_kernel<<<N_ASSOC / 64, 64, 0, stream>>>(S2, ovl_v, K, amask, nullptr, 0, Va, N_ASSOC, 4);
    ovl_kernel<<<16, 256, 0, stream>>>(amask, N_ASSOC / 16, ovl_a);
    // motor layer, CS=4
    matvec16_kernel<N_ASSOC, 4><<<(N_MOTOR / 4) * 4, 256, 0, stream>>>(W_am, Va, S3, N_MOTOR);
    rec_kernel<<<N_MOTOR / 64, 64, 0, stream>>>(S3, ovl_a, K, mmask, out, N_MOTOR, nullptr, 0, 4);
}